// Round 1
// baseline (298.194 us; speedup 1.0000x reference)
//
#include <hip/hip_runtime.h>
#include <hip/hip_bf16.h>

typedef float  f32x4 __attribute__((ext_vector_type(4)));
typedef short  s16x8 __attribute__((ext_vector_type(8)));
typedef __bf16 b16x8 __attribute__((ext_vector_type(8)));

#define DI static __device__ __forceinline__

constexpr int BATCH = 2;
constexpr int C     = 256;
constexpr int T     = 4096;
constexpr int NG    = 32;
constexpr int CPG   = 8;    // channels per group
constexpr int NH    = 4;
constexpr int CH    = 64;   // channels per head

// ---- workspace layout (bytes) ----
constexpr size_t STATS_OFF = 0;                         // 64 * 2 * 4 = 512
constexpr size_t QKVW_OFF  = 4096;                      // 768*256*2  = 393216
constexpr size_t PROJW_OFF = QKVW_OFF + 393216;         // 256*256*2  = 131072
constexpr size_t XNT_OFF   = PROJW_OFF + 131072;        // 2*4096*256*2 = 4 MiB
constexpr size_t Q_OFF     = XNT_OFF + 4194304;         // 8*4096*64*2  = 4 MiB
constexpr size_t K_OFF     = Q_OFF + 4194304;
constexpr size_t V_OFF     = K_OFF + 4194304;
constexpr size_t H_OFF     = V_OFF + 4194304;           // total ~21.5 MiB

// ---- MFMA wrapper: SFINAE over operand vector type (short8 vs __bf16x8) ----
template <typename V>
DI auto mfma_try(V a, V b, f32x4 c, int)
    -> decltype(__builtin_amdgcn_mfma_f32_16x16x32_bf16(a, b, c, 0, 0, 0)) {
  return __builtin_amdgcn_mfma_f32_16x16x32_bf16(a, b, c, 0, 0, 0);
}
template <typename V>
DI f32x4 mfma_try(V a, V b, f32x4 c, long) {
  return __builtin_amdgcn_mfma_f32_16x16x32_bf16(
      __builtin_bit_cast(b16x8, a), __builtin_bit_cast(b16x8, b), c, 0, 0, 0);
}
DI f32x4 MFMA(s16x8 a, s16x8 b, f32x4 c) { return mfma_try(a, b, c, 0); }

DI unsigned short f2b(float f) {
  return __builtin_bit_cast(unsigned short, __float2bfloat16(f));
}
DI s16x8 ld8(const unsigned short* p) { return *(const s16x8*)p; }

// ---- 1) GroupNorm stats: one block per (b, group); group = contiguous 8*T floats ----
__global__ __launch_bounds__(256) void k_gnstats(const float* __restrict__ x,
                                                 float* __restrict__ stats) {
  int g = blockIdx.x;  // b*32 + grp  (contiguous since C = NG*CPG)
  const float4* p = (const float4*)(x + (size_t)g * CPG * T);
  float s = 0.f, ss = 0.f;
  for (int i = threadIdx.x; i < CPG * T / 4; i += 256) {
    float4 v = p[i];
    s  += v.x + v.y + v.z + v.w;
    ss += v.x * v.x + v.y * v.y + v.z * v.z + v.w * v.w;
  }
#pragma unroll
  for (int off = 32; off > 0; off >>= 1) {
    s  += __shfl_down(s, off);
    ss += __shfl_down(ss, off);
  }
  __shared__ float sm[4], sm2[4];
  int wid = threadIdx.x >> 6;
  if ((threadIdx.x & 63) == 0) { sm[wid] = s; sm2[wid] = ss; }
  __syncthreads();
  if (threadIdx.x == 0) {
    float S  = sm[0] + sm[1] + sm[2] + sm[3];
    float SS = sm2[0] + sm2[1] + sm2[2] + sm2[3];
    const float inv = 1.f / (float)(CPG * T);
    float mu  = S * inv;
    float var = SS * inv - mu * mu;
    stats[2 * g]     = mu;
    stats[2 * g + 1] = rsqrtf(var + 1e-5f);
  }
}

// ---- 2) weights fp32 -> bf16 ----
__global__ __launch_bounds__(256) void k_convw(const float* __restrict__ qkvw,
                                               const float* __restrict__ projw,
                                               unsigned short* __restrict__ qwb,
                                               unsigned short* __restrict__ pwb) {
  int i = blockIdx.x * 256 + threadIdx.x;
  if (i < 3 * C * C) qwb[i] = f2b(qkvw[i]);
  if (i < C * C)     pwb[i] = f2b(projw[i]);
}

// ---- 3) GN apply + transpose -> xnT[b][t][c] (bf16) ----
__global__ __launch_bounds__(256) void k_gnapply(const float* __restrict__ x,
                                                 const float* __restrict__ stats,
                                                 const float* __restrict__ gnw,
                                                 const float* __restrict__ gnb,
                                                 unsigned short* __restrict__ xnT) {
  __shared__ float tile[64][65];
  int b = blockIdx.z, c0 = blockIdx.y * 64, t0 = blockIdx.x * 64;
  int tid = threadIdx.x;
  int tl = tid & 63, cq = tid >> 6;
#pragma unroll
  for (int i = 0; i < 16; i++) {
    int c = c0 + cq + i * 4;
    float mu  = stats[2 * (b * NG + c / CPG)];
    float rsd = stats[2 * (b * NG + c / CPG) + 1];
    float v = x[((size_t)b * C + c) * T + t0 + tl];
    tile[cq + i * 4][tl] = (v - mu) * rsd * gnw[c] + gnb[c];
  }
  __syncthreads();
#pragma unroll
  for (int i = 0; i < 16; i++) {
    int tr = cq + i * 4;  // t_local
    xnT[((size_t)b * T + t0 + tr) * C + c0 + tl] = f2b(tile[tl][tr]);
  }
}

// ---- 4) QKV GEMM: D[o][t] = sum_c W[o][c] * xnT[t][c]; scatter to Q/K ([bh][t][64]) and V ([bh][64][t]) ----
__global__ __launch_bounds__(256) void k_qkv(const unsigned short* __restrict__ wq,
                                             const float* __restrict__ bias,
                                             const unsigned short* __restrict__ xnT,
                                             unsigned short* __restrict__ qb,
                                             unsigned short* __restrict__ kb,
                                             unsigned short* __restrict__ vb) {
  int b = blockIdx.z;
  int o0 = blockIdx.y * 64;
  int t0 = blockIdx.x * 64;
  int lane = threadIdx.x & 63, wid = threadIdx.x >> 6;
  int lr = lane & 15, lhi = lane >> 4;
  int mo = o0 + wid * 16;
  const unsigned short* xp = xnT + (size_t)b * T * C;
  f32x4 acc[4] = {};
  for (int kc = 0; kc < C; kc += 32) {
    s16x8 af = ld8(wq + (size_t)(mo + lr) * C + kc + lhi * 8);
#pragma unroll
    for (int n = 0; n < 4; n++) {
      s16x8 bf = ld8(xp + (size_t)(t0 + n * 16 + lr) * C + kc + lhi * 8);
      acc[n] = MFMA(af, bf, acc[n]);
    }
  }
  // o = h*192 + r ; r<64:Q, <128:K, <192:V. o0 is a multiple of 64 so whole block is one region.
  int region = (o0 >> 6) % 3;
  int h = o0 / 192;
  int bh = b * NH + h;
  int obase = mo + lhi * 4;
  int rbase = obase - h * 192 - region * 64;
#pragma unroll
  for (int n = 0; n < 4; n++) {
    int t = t0 + n * 16 + lr;
    if (region < 2) {
      unsigned short pk[4];
#pragma unroll
      for (int j = 0; j < 4; j++) pk[j] = f2b(acc[n][j] + bias[obase + j]);
      unsigned short* dst = (region == 0 ? qb : kb) + ((size_t)bh * T + t) * CH + rbase;
      *(ushort4*)dst = make_ushort4(pk[0], pk[1], pk[2], pk[3]);
    } else {
#pragma unroll
      for (int j = 0; j < 4; j++)
        vb[((size_t)bh * CH + rbase + j) * T + t] = f2b(acc[n][j] + bias[obase + j]);
    }
  }
}

// ---- 5) Flash attention: block = (bh, 64 Q rows); wave = 16 rows; online softmax ----
__global__ __launch_bounds__(256) void k_attn(const unsigned short* __restrict__ qb,
                                              const unsigned short* __restrict__ kb,
                                              const unsigned short* __restrict__ vb,
                                              unsigned short* __restrict__ hb) {
  int bh = blockIdx.y;
  int wid = threadIdx.x >> 6;
  int lane = threadIdx.x & 63;
  int lr = lane & 15, lhi = lane >> 4;
  int t0 = blockIdx.x * 64 + wid * 16;
  const unsigned short* qp = qb + (size_t)bh * T * CH;
  const unsigned short* kp = kb + (size_t)bh * T * CH;
  const unsigned short* vp = vb + (size_t)bh * CH * T;
  s16x8 qf0 = ld8(qp + (size_t)(t0 + lr) * CH + lhi * 8);
  s16x8 qf1 = ld8(qp + (size_t)(t0 + lr) * CH + 32 + lhi * 8);
  f32x4 oacc[4] = {};
  float m[4], l[4];
#pragma unroll
  for (int j = 0; j < 4; j++) { m[j] = -1e30f; l[j] = 0.f; }
  __shared__ unsigned short plds[4][16][72];  // per-wave P tile, stride 144B (2-way alias only)
  unsigned short (*pw)[72] = plds[wid];
  const float sc = 0.125f;  // (d^-0.25)^2 = 1/sqrt(64)

  for (int s0 = 0; s0 < T; s0 += 64) {
    f32x4 wacc[4] = {};
#pragma unroll
    for (int n = 0; n < 4; n++) {
      const unsigned short* kr = kp + (size_t)(s0 + n * 16 + lr) * CH;
      wacc[n] = MFMA(qf0, ld8(kr + lhi * 8), wacc[n]);
      wacc[n] = MFMA(qf1, ld8(kr + 32 + lhi * 8), wacc[n]);
    }
    float tmax[4];
#pragma unroll
    for (int j = 0; j < 4; j++)
      tmax[j] = sc * fmaxf(fmaxf(wacc[0][j], wacc[1][j]), fmaxf(wacc[2][j], wacc[3][j]));
#pragma unroll
    for (int mask = 1; mask < 16; mask <<= 1)
#pragma unroll
      for (int j = 0; j < 4; j++) tmax[j] = fmaxf(tmax[j], __shfl_xor(tmax[j], mask));
    float alpha[4], rs[4];
#pragma unroll
    for (int j = 0; j < 4; j++) {
      float mn = fmaxf(m[j], tmax[j]);
      alpha[j] = __expf(m[j] - mn);
      m[j] = mn;
      rs[j] = 0.f;
    }
#pragma unroll
    for (int n = 0; n < 4; n++)
#pragma unroll
      for (int j = 0; j < 4; j++) {
        float p = __expf(wacc[n][j] * sc - m[j]);
        rs[j] += p;
        pw[lhi * 4 + j][n * 16 + lr] = f2b(p);  // W D-layout -> LDS [row][col]
      }
#pragma unroll
    for (int mask = 1; mask < 16; mask <<= 1)
#pragma unroll
      for (int j = 0; j < 4; j++) rs[j] += __shfl_xor(rs[j], mask);
#pragma unroll
    for (int j = 0; j < 4; j++) l[j] = l[j] * alpha[j] + rs[j];
#pragma unroll
    for (int nc = 0; nc < 4; nc++)
#pragma unroll
      for (int j = 0; j < 4; j++) oacc[nc][j] *= alpha[j];
    // P as MFMA A-operand (intra-wave LDS RAW; compiler inserts lgkmcnt wait)
    s16x8 pf0 = ld8(&pw[lr][lhi * 8]);
    s16x8 pf1 = ld8(&pw[lr][32 + lhi * 8]);
#pragma unroll
    for (int nc = 0; nc < 4; nc++) {
      const unsigned short* vr = vp + (size_t)(nc * 16 + lr) * T + s0;
      oacc[nc] = MFMA(pf0, ld8(vr + lhi * 8), oacc[nc]);
      oacc[nc] = MFMA(pf1, ld8(vr + 32 + lhi * 8), oacc[nc]);
    }
  }
  unsigned short* hp = hb + (size_t)bh * T * CH;
#pragma unroll
  for (int nc = 0; nc < 4; nc++)
#pragma unroll
    for (int j = 0; j < 4; j++)
      hp[(size_t)(t0 + lhi * 4 + j) * CH + nc * 16 + lr] = f2b(oacc[nc][j] / l[j]);
}

// ---- 6) proj GEMM + bias + residual -> out fp32 ----
__global__ __launch_bounds__(256) void k_proj(const unsigned short* __restrict__ wp,
                                              const float* __restrict__ bias,
                                              const unsigned short* __restrict__ hb,
                                              const float* __restrict__ x,
                                              float* __restrict__ out) {
  int b = blockIdx.z, o0 = blockIdx.y * 64, t0 = blockIdx.x * 64;
  int lane = threadIdx.x & 63, wid = threadIdx.x >> 6;
  int lr = lane & 15, lhi = lane >> 4;
  int mo = o0 + wid * 16;
  f32x4 acc[4] = {};
  for (int kc = 0; kc < C; kc += 32) {
    s16x8 af = ld8(wp + (size_t)(mo + lr) * C + kc + lhi * 8);
    int head = kc >> 6;          // k-chunk of 32 never crosses a 64-channel head
    int coff = (kc & 63) + lhi * 8;
#pragma unroll
    for (int n = 0; n < 4; n++) {
      s16x8 bf = ld8(hb + ((size_t)(b * NH + head) * T + t0 + n * 16 + lr) * CH + coff);
      acc[n] = MFMA(af, bf, acc[n]);
    }
  }
#pragma unroll
  for (int n = 0; n < 4; n++) {
    int t = t0 + n * 16 + lr;
#pragma unroll
    for (int j = 0; j < 4; j++) {
      int o = mo + lhi * 4 + j;
      size_t idx = ((size_t)b * C + o) * T + t;
      out[idx] = x[idx] + bias[o] + acc[n][j];
    }
  }
}

extern "C" void kernel_launch(void* const* d_in, const int* in_sizes, int n_in,
                              void* d_out, int out_size, void* d_ws, size_t ws_size,
                              hipStream_t stream) {
  const float* x     = (const float*)d_in[0];
  const float* gnw   = (const float*)d_in[1];
  const float* gnb   = (const float*)d_in[2];
  const float* qkvw  = (const float*)d_in[3];
  const float* qkvb  = (const float*)d_in[4];
  const float* projw = (const float*)d_in[5];
  const float* projb = (const float*)d_in[6];
  float* out = (float*)d_out;
  char* ws = (char*)d_ws;

  float* stats          = (float*)(ws + STATS_OFF);
  unsigned short* qw_b  = (unsigned short*)(ws + QKVW_OFF);
  unsigned short* pw_b  = (unsigned short*)(ws + PROJW_OFF);
  unsigned short* xnT   = (unsigned short*)(ws + XNT_OFF);
  unsigned short* qbuf  = (unsigned short*)(ws + Q_OFF);
  unsigned short* kbuf  = (unsigned short*)(ws + K_OFF);
  unsigned short* vbuf  = (unsigned short*)(ws + V_OFF);
  unsigned short* hbuf  = (unsigned short*)(ws + H_OFF);

  k_gnstats<<<dim3(BATCH * NG), dim3(256), 0, stream>>>(x, stats);
  k_convw  <<<dim3((3 * C * C + 255) / 256), dim3(256), 0, stream>>>(qkvw, projw, qw_b, pw_b);
  k_gnapply<<<dim3(T / 64, C / 64, BATCH), dim3(256), 0, stream>>>(x, stats, gnw, gnb, xnT);
  k_qkv    <<<dim3(T / 64, (3 * C) / 64, BATCH), dim3(256), 0, stream>>>(qw_b, qkvb, xnT, qbuf, kbuf, vbuf);
  k_attn   <<<dim3(T / 64, BATCH * NH), dim3(256), 0, stream>>>(qbuf, kbuf, vbuf, hbuf);
  k_proj   <<<dim3(T / 64, C / 64, BATCH), dim3(256), 0, stream>>>(pw_b, projb, hbuf, x, out);
}

// Round 2
// 111.441 us; speedup vs baseline: 2.6758x; 2.6758x over previous
//
#include <hip/hip_runtime.h>
#include <hip/hip_bf16.h>

typedef float  f32x4  __attribute__((ext_vector_type(4)));
typedef float  f32x16 __attribute__((ext_vector_type(16)));
typedef short  s16x8  __attribute__((ext_vector_type(8)));
typedef __bf16 b16x8  __attribute__((ext_vector_type(8)));
typedef unsigned int u32x4 __attribute__((ext_vector_type(4)));

#define DI static __device__ __forceinline__

constexpr int BATCH = 2;
constexpr int C     = 256;
constexpr int T     = 4096;
constexpr int NG    = 32;
constexpr int CPG   = 8;    // channels per group
constexpr int NH    = 4;
constexpr int CH    = 64;   // channels per head

// ---- workspace layout (bytes) ----
constexpr size_t STATS_OFF = 0;
constexpr size_t QKVW_OFF  = 4096;
constexpr size_t PROJW_OFF = QKVW_OFF + 393216;
constexpr size_t XNT_OFF   = PROJW_OFF + 131072;
constexpr size_t Q_OFF     = XNT_OFF + 4194304;
constexpr size_t K_OFF     = Q_OFF + 4194304;
constexpr size_t V_OFF     = K_OFF + 4194304;
constexpr size_t H_OFF     = V_OFF + 4194304;

// ---- MFMA wrappers: SFINAE over operand vector type (short8 vs __bf16x8) ----
template <typename V>
DI auto mfma_try(V a, V b, f32x4 c, int)
    -> decltype(__builtin_amdgcn_mfma_f32_16x16x32_bf16(a, b, c, 0, 0, 0)) {
  return __builtin_amdgcn_mfma_f32_16x16x32_bf16(a, b, c, 0, 0, 0);
}
template <typename V>
DI f32x4 mfma_try(V a, V b, f32x4 c, long) {
  return __builtin_amdgcn_mfma_f32_16x16x32_bf16(
      __builtin_bit_cast(b16x8, a), __builtin_bit_cast(b16x8, b), c, 0, 0, 0);
}
DI f32x4 MFMA(s16x8 a, s16x8 b, f32x4 c) { return mfma_try(a, b, c, 0); }

template <typename V>
DI auto mfma32_try(V a, V b, f32x16 c, int)
    -> decltype(__builtin_amdgcn_mfma_f32_32x32x16_bf16(a, b, c, 0, 0, 0)) {
  return __builtin_amdgcn_mfma_f32_32x32x16_bf16(a, b, c, 0, 0, 0);
}
template <typename V>
DI f32x16 mfma32_try(V a, V b, f32x16 c, long) {
  return __builtin_amdgcn_mfma_f32_32x32x16_bf16(
      __builtin_bit_cast(b16x8, a), __builtin_bit_cast(b16x8, b), c, 0, 0, 0);
}
DI f32x16 MFMA32(s16x8 a, s16x8 b, f32x16 c) { return mfma32_try(a, b, c, 0); }

DI unsigned short f2b(float f) {
  return __builtin_bit_cast(unsigned short, __float2bfloat16(f));
}
DI s16x8 ld8(const unsigned short* p) { return *(const s16x8*)p; }

DI float exp2f_(float x) {
#if __has_builtin(__builtin_amdgcn_exp2f)
  return __builtin_amdgcn_exp2f(x);
#else
  return exp2f(x);
#endif
}

DI unsigned cvtpk(float lo, float hi) {
  unsigned r;
  asm("v_cvt_pk_bf16_f32 %0, %1, %2" : "=v"(r) : "v"(lo), "v"(hi));
  return r;
}

// permlane32_swap: a' = [a.lo | b.lo], b' = [a.hi | b.hi]
DI void swap32(unsigned& a, unsigned& b) {
#if __has_builtin(__builtin_amdgcn_permlane32_swap)
  auto r = __builtin_amdgcn_permlane32_swap((int)a, (int)b, false, false);
  a = (unsigned)r[0];
  b = (unsigned)r[1];
#else
  unsigned as = (unsigned)__shfl_xor((int)a, 32);
  unsigned bs = (unsigned)__shfl_xor((int)b, 32);
  if (threadIdx.x & 32) a = bs; else b = as;
#endif
}

DI void stage16(const void* g, void* l) {
  __builtin_amdgcn_global_load_lds((__attribute__((address_space(1))) const void*)g,
                                   (__attribute__((address_space(3))) void*)l, 16, 0, 0);
}

// ---- 1) GroupNorm stats ----
__global__ __launch_bounds__(256) void k_gnstats(const float* __restrict__ x,
                                                 float* __restrict__ stats) {
  int g = blockIdx.x;
  const float4* p = (const float4*)(x + (size_t)g * CPG * T);
  float s = 0.f, ss = 0.f;
  for (int i = threadIdx.x; i < CPG * T / 4; i += 256) {
    float4 v = p[i];
    s  += v.x + v.y + v.z + v.w;
    ss += v.x * v.x + v.y * v.y + v.z * v.z + v.w * v.w;
  }
#pragma unroll
  for (int off = 32; off > 0; off >>= 1) {
    s  += __shfl_down(s, off);
    ss += __shfl_down(ss, off);
  }
  __shared__ float sm[4], sm2[4];
  int wid = threadIdx.x >> 6;
  if ((threadIdx.x & 63) == 0) { sm[wid] = s; sm2[wid] = ss; }
  __syncthreads();
  if (threadIdx.x == 0) {
    float S  = sm[0] + sm[1] + sm[2] + sm[3];
    float SS = sm2[0] + sm2[1] + sm2[2] + sm2[3];
    const float inv = 1.f / (float)(CPG * T);
    float mu  = S * inv;
    float var = SS * inv - mu * mu;
    stats[2 * g]     = mu;
    stats[2 * g + 1] = rsqrtf(var + 1e-5f);
  }
}

// ---- 2) weights fp32 -> bf16 ----
__global__ __launch_bounds__(256) void k_convw(const float* __restrict__ qkvw,
                                               const float* __restrict__ projw,
                                               unsigned short* __restrict__ qwb,
                                               unsigned short* __restrict__ pwb) {
  int i = blockIdx.x * 256 + threadIdx.x;
  if (i < 3 * C * C) qwb[i] = f2b(qkvw[i]);
  if (i < C * C)     pwb[i] = f2b(projw[i]);
}

// ---- 3) GN apply + transpose -> xnT[b][t][c] (bf16) ----
__global__ __launch_bounds__(256) void k_gnapply(const float* __restrict__ x,
                                                 const float* __restrict__ stats,
                                                 const float* __restrict__ gnw,
                                                 const float* __restrict__ gnb,
                                                 unsigned short* __restrict__ xnT) {
  __shared__ float tile[64][65];
  int b = blockIdx.z, c0 = blockIdx.y * 64, t0 = blockIdx.x * 64;
  int tid = threadIdx.x;
  int tl = tid & 63, cq = tid >> 6;
#pragma unroll
  for (int i = 0; i < 16; i++) {
    int c = c0 + cq + i * 4;
    float mu  = stats[2 * (b * NG + c / CPG)];
    float rsd = stats[2 * (b * NG + c / CPG) + 1];
    float v = x[((size_t)b * C + c) * T + t0 + tl];
    tile[cq + i * 4][tl] = (v - mu) * rsd * gnw[c] + gnb[c];
  }
  __syncthreads();
#pragma unroll
  for (int i = 0; i < 16; i++) {
    int tr = cq + i * 4;
    xnT[((size_t)b * T + t0 + tr) * C + c0 + tl] = f2b(tile[tl][tr]);
  }
}

// ---- 4) QKV GEMM -> Q,K:[bh][t][64], V:[bh][64][t] ----
__global__ __launch_bounds__(256) void k_qkv(const unsigned short* __restrict__ wq,
                                             const float* __restrict__ bias,
                                             const unsigned short* __restrict__ xnT,
                                             unsigned short* __restrict__ qb,
                                             unsigned short* __restrict__ kb,
                                             unsigned short* __restrict__ vb) {
  int b = blockIdx.z;
  int o0 = blockIdx.y * 64;
  int t0 = blockIdx.x * 64;
  int lane = threadIdx.x & 63, wid = threadIdx.x >> 6;
  int lr = lane & 15, lhi = lane >> 4;
  int mo = o0 + wid * 16;
  const unsigned short* xp = xnT + (size_t)b * T * C;
  f32x4 acc[4] = {};
  for (int kc = 0; kc < C; kc += 32) {
    s16x8 af = ld8(wq + (size_t)(mo + lr) * C + kc + lhi * 8);
#pragma unroll
    for (int n = 0; n < 4; n++) {
      s16x8 bf = ld8(xp + (size_t)(t0 + n * 16 + lr) * C + kc + lhi * 8);
      acc[n] = MFMA(af, bf, acc[n]);
    }
  }
  int region = (o0 >> 6) % 3;
  int h = o0 / 192;
  int bh = b * NH + h;
  int obase = mo + lhi * 4;
  int rbase = obase - h * 192 - region * 64;
#pragma unroll
  for (int n = 0; n < 4; n++) {
    int t = t0 + n * 16 + lr;
    if (region < 2) {
      unsigned short pk[4];
#pragma unroll
      for (int j = 0; j < 4; j++) pk[j] = f2b(acc[n][j] + bias[obase + j]);
      unsigned short* dst = (region == 0 ? qb : kb) + ((size_t)bh * T + t) * CH + rbase;
      *(ushort4*)dst = make_ushort4(pk[0], pk[1], pk[2], pk[3]);
    } else {
#pragma unroll
      for (int j = 0; j < 4; j++)
        vb[((size_t)bh * CH + rbase + j) * T + t] = f2b(acc[n][j] + bias[obase + j]);
    }
  }
}

// ---- 5) Flash attention v2: 8 waves (4 q-subtiles x 2 s-groups), 32x32 MFMA,
//         swapped QK^T, LDS-staged K/V (dbuf + XOR swizzle), exp2 softmax ----
__global__ __launch_bounds__(512, 2) void k_attn2(const unsigned short* __restrict__ qb,
                                                  const unsigned short* __restrict__ kb,
                                                  const unsigned short* __restrict__ vb,
                                                  unsigned short* __restrict__ hb) {
  int bid = blockIdx.x;
  int lin = (bid & 7) * 32 + (bid >> 3);  // XCD swizzle: nwg=256 divisible by 8
  int qt = lin & 31;
  int bh = lin >> 5;
  int tid = threadIdx.x;
  int wid = tid >> 6, lane = tid & 63;
  int l31 = lane & 31, h = lane >> 5;
  int wq = wid & 3, g = wid >> 2;
  int qbase = qt * 128 + wq * 32;

  const unsigned short* qp = qb + (size_t)bh * T * CH;
  const unsigned short* kp = kb + (size_t)bh * T * CH;
  const unsigned short* vp = vb + (size_t)bh * CH * T;
  unsigned short* hp = hb + (size_t)bh * T * CH;

  __shared__ __align__(16) char smem[65536];  // [g][buf] 16KB slabs: K(8K)|V(8K)

  // Q fragments (B-operand: lane j=q holds ch = kc*16 + h*8 + r)
  s16x8 qf[4];
#pragma unroll
  for (int kc = 0; kc < 4; kc++)
    qf[kc] = ld8(qp + (size_t)(qbase + l31) * CH + kc * 16 + h * 8);

  f32x16 O0 = {}, O1 = {};
  float m = -1e30f, lsum = 0.f;
  const float sc2 = 0.18033688011f;  // 0.125 * log2(e)

  const int NT = T / 128;  // 32 s-tiles per group
  int srow = lane >> 3;    // staging: 8 rows per 1KB issue
  int su = lane & 7;

#define STAGE(BUF, TT)                                                              \
  {                                                                                 \
    int s0_ = g * (T / 2) + (TT) * 64;                                              \
    char* slab_ = smem + g * 32768 + (BUF) * 16384;                                 \
    if (wq < 2) {                                                                   \
      _Pragma("unroll") for (int i_ = 0; i_ < 4; i_++) {                            \
        int j_ = wq * 4 + i_;                                                       \
        int row_ = j_ * 8 + srow;                                                   \
        stage16(kp + (size_t)(s0_ + row_) * CH + (su ^ (row_ & 7)) * 8,             \
                slab_ + j_ * 1024);                                                 \
      }                                                                             \
    } else {                                                                        \
      _Pragma("unroll") for (int i_ = 0; i_ < 4; i_++) {                            \
        int j_ = (wq - 2) * 4 + i_;                                                 \
        int row_ = j_ * 8 + srow;                                                   \
        stage16(vp + (size_t)row_ * T + s0_ + (su ^ (row_ & 7)) * 8,                \
                slab_ + 8192 + j_ * 1024);                                          \
      }                                                                             \
    }                                                                               \
  }

  int buf = 0;
  STAGE(0, 0);
  __syncthreads();

  for (int t = 0; t < NT; ++t) {
    if (t + 1 < NT) STAGE(buf ^ 1, t + 1);
    const unsigned short* Kt = (const unsigned short*)(smem + g * 32768 + buf * 16384);
    const unsigned short* Vt = Kt + 4096;  // +8KB

    // QK^T (swapped): S^T[s][q] = mfma(A=K, B=Q)
    f32x16 S0 = {}, S1 = {};
    int row0 = l31, row1 = 32 + l31;
    int rsw = row0 & 7;  // row0&7 == row1&7
#pragma unroll
    for (int kc = 0; kc < 4; kc++) {
      s16x8 k0 = ld8(Kt + row0 * 64 + ((kc * 2 + h) ^ rsw) * 8);
      s16x8 k1 = ld8(Kt + row1 * 64 + ((kc * 2 + h) ^ rsw) * 8);
      S0 = MFMA32(k0, qf[kc], S0);
      S1 = MFMA32(k1, qf[kc], S1);
    }

    // online softmax (exp2 domain), defer-max THR=8
    float mx = S0[0];
#pragma unroll
    for (int j = 1; j < 16; j++) mx = fmaxf(mx, S0[j]);
#pragma unroll
    for (int j = 0; j < 16; j++) mx = fmaxf(mx, S1[j]);
    mx = fmaxf(mx, __shfl_xor(mx, 32));
    float cand = mx * sc2;
    if (!__all(cand <= m + 8.f)) {
      float mn = fmaxf(m, cand);
      float a = exp2f_(m - mn);
      m = mn;
      lsum *= a;
#pragma unroll
      for (int j = 0; j < 16; j++) { O0[j] *= a; O1[j] *= a; }
    }
    float ps = 0.f;
#pragma unroll
    for (int j = 0; j < 16; j++) {
      S0[j] = exp2f_(__builtin_fmaf(S0[j], sc2, -m));
      ps += S0[j];
    }
#pragma unroll
    for (int j = 0; j < 16; j++) {
      S1[j] = exp2f_(__builtin_fmaf(S1[j], sc2, -m));
      ps += S1[j];
    }
    lsum += ps;

    // pack P -> bf16 B-fragments (cvt_pk + permlane32_swap), per 32-s block
    unsigned a0, a1, a2, a3;
    a0 = cvtpk(S0[0], S0[1]);  a1 = cvtpk(S0[2], S0[3]);
    a2 = cvtpk(S0[4], S0[5]);  a3 = cvtpk(S0[6], S0[7]);
    swap32(a0, a2); swap32(a1, a3);
    u32x4 pkA = {a0, a1, a2, a3};  // s-chunk 0 (s 0..15)
    a0 = cvtpk(S0[8], S0[9]);   a1 = cvtpk(S0[10], S0[11]);
    a2 = cvtpk(S0[12], S0[13]); a3 = cvtpk(S0[14], S0[15]);
    swap32(a0, a2); swap32(a1, a3);
    u32x4 pkB = {a0, a1, a2, a3};  // s-chunk 1 (s 16..31)
    a0 = cvtpk(S1[0], S1[1]);  a1 = cvtpk(S1[2], S1[3]);
    a2 = cvtpk(S1[4], S1[5]);  a3 = cvtpk(S1[6], S1[7]);
    swap32(a0, a2); swap32(a1, a3);
    u32x4 pkC = {a0, a1, a2, a3};  // s-chunk 2
    a0 = cvtpk(S1[8], S1[9]);   a1 = cvtpk(S1[10], S1[11]);
    a2 = cvtpk(S1[12], S1[13]); a3 = cvtpk(S1[14], S1[15]);
    swap32(a0, a2); swap32(a1, a3);
    u32x4 pkD = {a0, a1, a2, a3};  // s-chunk 3

    // PV: O^T[ch][q] += mfma(A=V^T, B=P)
#pragma unroll
    for (int sch = 0; sch < 4; sch++) {
      s16x8 pf = __builtin_bit_cast(s16x8, sch == 0 ? pkA : sch == 1 ? pkB : sch == 2 ? pkC : pkD);
      s16x8 v0 = ld8(Vt + row0 * 64 + ((sch * 2 + h) ^ rsw) * 8);
      s16x8 v1 = ld8(Vt + row1 * 64 + ((sch * 2 + h) ^ rsw) * 8);
      O0 = MFMA32(v0, pf, O0);
      O1 = MFMA32(v1, pf, O1);
    }
    __syncthreads();
    buf ^= 1;
  }

  // combine s-split pairs (wid, wid+4) and write out
  lsum += __shfl_xor(lsum, 32);
  float* cmb = (float*)smem;
  if (wid >= 4) {
    float* dst = cmb + ((wid - 4) * 64 + lane) * 34;
#pragma unroll
    for (int j = 0; j < 16; j++) { dst[j] = O0[j]; dst[16 + j] = O1[j]; }
    dst[32] = m;
    dst[33] = lsum;
  }
  __syncthreads();
  if (wid < 4) {
    const float* src = cmb + (wid * 64 + lane) * 34;
    float m2 = src[32], l2 = src[33];
    float mm = fmaxf(m, m2);
    float b1 = exp2f_(m - mm), b2 = exp2f_(m2 - mm);
    float linv = 1.f / (lsum * b1 + l2 * b2);
    b1 *= linv;
    b2 *= linv;
    int q = qbase + l31;
#pragma unroll
    for (int j = 0; j < 16; j += 2) {
      float x0 = O0[j] * b1 + src[j] * b2;
      float x1 = O0[j + 1] * b1 + src[j + 1] * b2;
      int ch = (j & 3) + 8 * (j >> 2) + 4 * h;
      *(unsigned*)(hp + (size_t)q * CH + ch) = cvtpk(x0, x1);
      float y0 = O1[j] * b1 + src[16 + j] * b2;
      float y1 = O1[j + 1] * b1 + src[16 + j + 1] * b2;
      *(unsigned*)(hp + (size_t)q * CH + 32 + ch) = cvtpk(y0, y1);
    }
  }
}

// ---- 6) proj GEMM + bias + residual -> out fp32 ----
__global__ __launch_bounds__(256) void k_proj(const unsigned short* __restrict__ wp,
                                              const float* __restrict__ bias,
                                              const unsigned short* __restrict__ hb,
                                              const float* __restrict__ x,
                                              float* __restrict__ out) {
  int b = blockIdx.z, o0 = blockIdx.y * 64, t0 = blockIdx.x * 64;
  int lane = threadIdx.x & 63, wid = threadIdx.x >> 6;
  int lr = lane & 15, lhi = lane >> 4;
  int mo = o0 + wid * 16;
  f32x4 acc[4] = {};
  for (int kc = 0; kc < C; kc += 32) {
    s16x8 af = ld8(wp + (size_t)(mo + lr) * C + kc + lhi * 8);
    int head = kc >> 6;
    int coff = (kc & 63) + lhi * 8;
#pragma unroll
    for (int n = 0; n < 4; n++) {
      s16x8 bf = ld8(hb + ((size_t)(b * NH + head) * T + t0 + n * 16 + lr) * CH + coff);
      acc[n] = MFMA(af, bf, acc[n]);
    }
  }
#pragma unroll
  for (int n = 0; n < 4; n++) {
    int t = t0 + n * 16 + lr;
#pragma unroll
    for (int j = 0; j < 4; j++) {
      int o = mo + lhi * 4 + j;
      size_t idx = ((size_t)b * C + o) * T + t;
      out[idx] = x[idx] + bias[o] + acc[n][j];
    }
  }
}

extern "C" void kernel_launch(void* const* d_in, const int* in_sizes, int n_in,
                              void* d_out, int out_size, void* d_ws, size_t ws_size,
                              hipStream_t stream) {
  const float* x     = (const float*)d_in[0];
  const float* gnw   = (const float*)d_in[1];
  const float* gnb   = (const float*)d_in[2];
  const float* qkvw  = (const float*)d_in[3];
  const float* qkvb  = (const float*)d_in[4];
  const float* projw = (const float*)d_in[5];
  const float* projb = (const float*)d_in[6];
  float* out = (float*)d_out;
  char* ws = (char*)d_ws;

  float* stats          = (float*)(ws + STATS_OFF);
  unsigned short* qw_b  = (unsigned short*)(ws + QKVW_OFF);
  unsigned short* pw_b  = (unsigned short*)(ws + PROJW_OFF);
  unsigned short* xnT   = (unsigned short*)(ws + XNT_OFF);
  unsigned short* qbuf  = (unsigned short*)(ws + Q_OFF);
  unsigned short* kbuf  = (unsigned short*)(ws + K_OFF);
  unsigned short* vbuf  = (unsigned short*)(ws + V_OFF);
  unsigned short* hbuf  = (unsigned short*)(ws + H_OFF);

  k_gnstats<<<dim3(BATCH * NG), dim3(256), 0, stream>>>(x, stats);
  k_convw  <<<dim3((3 * C * C + 255) / 256), dim3(256), 0, stream>>>(qkvw, projw, qw_b, pw_b);
  k_gnapply<<<dim3(T / 64, C / 64, BATCH), dim3(256), 0, stream>>>(x, stats, gnw, gnb, xnT);
  k_qkv    <<<dim3(T / 64, (3 * C) / 64, BATCH), dim3(256), 0, stream>>>(qw_b, qkvb, xnT, qbuf, kbuf, vbuf);
  k_attn2  <<<dim3(256), dim3(512), 0, stream>>>(qbuf, kbuf, vbuf, hbuf);
  k_proj   <<<dim3(T / 64, C / 64, BATCH), dim3(256), 0, stream>>>(pw_b, projb, hbuf, x, out);
}